// Round 1
// baseline (344.601 us; speedup 1.0000x reference)
//
#include <hip/hip_runtime.h>

// Problem constants
#define B     4
#define LQ    4096
#define LK    5119
#define D     512
#define CACHE 1024
#define MQ    (B * LQ)          // 16384
#define MK    (B * LK)          // 20476
#define MKP   20480             // padded to multiple of 128

typedef float  f32x4  __attribute__((ext_vector_type(4)));
typedef __bf16 bf16x8 __attribute__((ext_vector_type(8)));

// ---------------------------------------------------------------------------
// Kernel 1: per-row LayerNorm -> bf16.  One wave (64 threads) per row of 512.
// ---------------------------------------------------------------------------
__global__ __launch_bounds__(64) void ln_bf16_kernel(
    const float* __restrict__ x, const float* __restrict__ g,
    const float* __restrict__ bta, __bf16* __restrict__ o)
{
    const int r = blockIdx.x;
    const int t = threadIdx.x;
    const float* xr = x + (long)r * D;

    float v[8];
    float s = 0.f, ss = 0.f;
#pragma unroll
    for (int j = 0; j < 8; ++j) {
        v[j] = xr[t + 64 * j];
        s  += v[j];
        ss += v[j] * v[j];
    }
#pragma unroll
    for (int m = 1; m < 64; m <<= 1) {
        s  += __shfl_xor(s,  m, 64);
        ss += __shfl_xor(ss, m, 64);
    }
    const float mean = s * (1.f / (float)D);
    const float var  = ss * (1.f / (float)D) - mean * mean;
    const float rs   = rsqrtf(var + 1e-5f);

    __bf16* orow = o + (long)r * D;
#pragma unroll
    for (int j = 0; j < 8; ++j) {
        const int dd = t + 64 * j;
        const float y = (v[j] - mean) * rs * g[dd] + bta[dd];
        orow[dd] = (__bf16)y;
    }
}

// ---------------------------------------------------------------------------
// Kernel 2: W [512(k)][512(n)] f32  ->  Wt [512(n)][512(k)] bf16 (transposed)
// ---------------------------------------------------------------------------
__global__ __launch_bounds__(256) void wconv_kernel(
    const float* __restrict__ W, __bf16* __restrict__ Wt)
{
    const int n = blockIdx.x * 256 + threadIdx.x;
    const int k = blockIdx.y;
    Wt[(long)n * D + k] = (__bf16)W[(long)k * D + n];
}

// ---------------------------------------------------------------------------
// Kernel 3: MFMA GEMM  C[M,512] = A[M,512](bf16) x W[512,512] + bias, epilogue.
// Tile 128x128, 256 threads = 4 waves in 2x2, each wave 64x64 via 4x4 MFMA
// 16x16x32 tiles.  Wt is B transposed: Wt[n][k].
// mode 0: C = relu(acc + bias);  mode 1: C = C_old * (acc + bias)
// ---------------------------------------------------------------------------
#define BM  128
#define BN  128
#define BK  32
#define LDK 40   // padded LDS k-stride (bf16 units) -> 80B rows, conflict-light

__global__ __launch_bounds__(256) void gemm_ep_kernel(
    const __bf16* __restrict__ A, const __bf16* __restrict__ Wt,
    const float* __restrict__ bias, float* __restrict__ C, int mode)
{
    __shared__ __attribute__((aligned(16))) __bf16 As[BM * LDK];
    __shared__ __attribute__((aligned(16))) __bf16 Bs[BN * LDK];

    const int mtile = blockIdx.x;
    const int ntile = blockIdx.y;
    const int tid   = threadIdx.x;
    const int lane  = tid & 63;
    const int wave  = tid >> 6;
    const int wm    = wave >> 1;     // 0..1
    const int wn    = wave & 1;      // 0..1
    const int quad  = lane >> 4;     // 0..3
    const int l16   = lane & 15;

    f32x4 acc[4][4];
#pragma unroll
    for (int i = 0; i < 4; ++i)
#pragma unroll
        for (int j = 0; j < 4; ++j)
            acc[i][j] = (f32x4){0.f, 0.f, 0.f, 0.f};

    const long arow0 = (long)mtile * BM;
    const long brow0 = (long)ntile * BN;
    const int  srow  = tid >> 2;        // 0..63
    const int  scol  = (tid & 3) * 8;   // 0,8,16,24

    for (int k0 = 0; k0 < D; k0 += BK) {
#pragma unroll
        for (int h = 0; h < 2; ++h) {
            const int r = srow + h * 64;
            *reinterpret_cast<uint4*>(&As[r * LDK + scol]) =
                *reinterpret_cast<const uint4*>(&A[(arow0 + r) * D + k0 + scol]);
            *reinterpret_cast<uint4*>(&Bs[r * LDK + scol]) =
                *reinterpret_cast<const uint4*>(&Wt[(brow0 + r) * D + k0 + scol]);
        }
        __syncthreads();

        bf16x8 af[4], bfr[4];
#pragma unroll
        for (int tm = 0; tm < 4; ++tm)
            af[tm] = *reinterpret_cast<const bf16x8*>(
                &As[(wm * 64 + tm * 16 + l16) * LDK + quad * 8]);
#pragma unroll
        for (int tn = 0; tn < 4; ++tn)
            bfr[tn] = *reinterpret_cast<const bf16x8*>(
                &Bs[(wn * 64 + tn * 16 + l16) * LDK + quad * 8]);

#pragma unroll
        for (int tm = 0; tm < 4; ++tm)
#pragma unroll
            for (int tn = 0; tn < 4; ++tn)
                acc[tm][tn] = __builtin_amdgcn_mfma_f32_16x16x32_bf16(
                    af[tm], bfr[tn], acc[tm][tn], 0, 0, 0);
        __syncthreads();
    }

    // Epilogue.  C/D layout: col = lane&15, row = quad*4 + reg.
#pragma unroll
    for (int tm = 0; tm < 4; ++tm) {
        const long row = arow0 + wm * 64 + tm * 16 + quad * 4;
#pragma unroll
        for (int tn = 0; tn < 4; ++tn) {
            const int col = (int)brow0 + wn * 64 + tn * 16 + l16;
            const float bv = bias[col];
            float* cp = &C[row * D + col];
#pragma unroll
            for (int r = 0; r < 4; ++r) {
                const float vv = acc[tm][tn][r] + bv;
                float* p = cp + (long)r * D;
                if (mode == 0) *p = fmaxf(vv, 0.f);
                else           *p = *p * vv;
            }
        }
    }
}

// ---------------------------------------------------------------------------
// Kernel 4: sliding-window sum (width 1024) over kv, times relu(qp).
// Block: 256 threads, each owns one d-column (of a 256-wide half); processes
// TI=128 consecutive query rows with a running sum.
// ---------------------------------------------------------------------------
#define TI 128

__global__ __launch_bounds__(256) void window_mul_kernel(
    const float* __restrict__ kv, const float* __restrict__ qpr,
    float* __restrict__ out)
{
    const int b     = blockIdx.z;
    const int dbase = blockIdx.y * 256;
    const int i0    = blockIdx.x * TI;
    const int d     = dbase + threadIdx.x;

    const float* kvb = kv + ((long)b * LK) * D + d;

    float s = 0.f;
#pragma unroll 8
    for (int t = 0; t < CACHE; ++t)
        s += kvb[(long)(i0 + t) * D];

    for (int i = i0; i < i0 + TI; ++i) {
        const long qoff = ((long)b * LQ + i) * D + d;
        out[qoff] = qpr[qoff] * s;
        // advance window (last update of the block is discarded; reads stay
        // within the padded 20480-row kv buffer)
        s += kvb[(long)(i + CACHE) * D] - kvb[(long)i * D];
    }
}

// ---------------------------------------------------------------------------
extern "C" void kernel_launch(void* const* d_in, const int* in_sizes, int n_in,
                              void* d_out, int out_size, void* d_ws, size_t ws_size,
                              hipStream_t stream)
{
    const float* q   = (const float*)d_in[0];
    const float* k   = (const float*)d_in[1];
    const float* v   = (const float*)d_in[2];
    const float* gq  = (const float*)d_in[3];
    const float* bq  = (const float*)d_in[4];
    const float* gk  = (const float*)d_in[5];
    const float* bk  = (const float*)d_in[6];
    const float* gv  = (const float*)d_in[7];
    const float* bv  = (const float*)d_in[8];
    const float* Wq  = (const float*)d_in[9];
    const float* bwq = (const float*)d_in[10];
    const float* Wk  = (const float*)d_in[11];
    const float* bwk = (const float*)d_in[12];
    const float* Wv  = (const float*)d_in[13];
    const float* bwv = (const float*)d_in[14];
    float* out = (float*)d_out;

    // Workspace layout
    char* ws = (char*)d_ws;
    __bf16* qn  = (__bf16*)ws;                       // [MQ ][D] bf16
    __bf16* kn  = qn + (long)MQ  * D;                // [MKP][D] bf16
    __bf16* vn  = kn + (long)MKP * D;                // [MKP][D] bf16
    float*  qp  = (float*)(vn + (long)MKP * D);      // [MQ ][D] f32  (relu(qp))
    float*  kv  = qp + (long)MQ * D;                 // [MKP][D] f32  (relu(kp), then kv)
    __bf16* wtq = (__bf16*)(kv + (long)MKP * D);     // [D][D] bf16 transposed
    __bf16* wtk = wtq + (long)D * D;
    __bf16* wtv = wtk + (long)D * D;

    // Zero the 4 padding rows of kn/vn (poisoned to 0xAA by the harness)
    hipMemsetAsync(kn + (long)MK * D, 0, (size_t)(MKP - MK) * D * sizeof(__bf16), stream);
    hipMemsetAsync(vn + (long)MK * D, 0, (size_t)(MKP - MK) * D * sizeof(__bf16), stream);

    // 1) LayerNorm -> bf16
    ln_bf16_kernel<<<MQ, 64, 0, stream>>>(q, gq, bq, qn);
    ln_bf16_kernel<<<MK, 64, 0, stream>>>(k, gk, bk, kn);
    ln_bf16_kernel<<<MK, 64, 0, stream>>>(v, gv, bv, vn);

    // 2) Weight transpose-convert
    wconv_kernel<<<dim3(2, D), 256, 0, stream>>>(Wq, wtq);
    wconv_kernel<<<dim3(2, D), 256, 0, stream>>>(Wk, wtk);
    wconv_kernel<<<dim3(2, D), 256, 0, stream>>>(Wv, wtv);

    // 3) GEMMs with fused epilogues
    gemm_ep_kernel<<<dim3(MQ  / BM, D / BN), 256, 0, stream>>>(qn, wtq, bwq, qp, 0); // relu(qp)
    gemm_ep_kernel<<<dim3(MKP / BM, D / BN), 256, 0, stream>>>(kn, wtk, bwk, kv, 0); // relu(kp)
    gemm_ep_kernel<<<dim3(MKP / BM, D / BN), 256, 0, stream>>>(vn, wtv, bwv, kv, 1); // kv = relu(kp)*vp

    // 4) Sliding-window sum x relu(qp)
    window_mul_kernel<<<dim3(LQ / TI, 2, B), 256, 0, stream>>>(kv, qp, out);
}

// Round 2
// 273.037 us; speedup vs baseline: 1.2621x; 1.2621x over previous
//
#include <hip/hip_runtime.h>

// Problem constants
#define B     4
#define LQ    4096
#define LK    5119
#define D     512
#define CACHE 1024
#define MQ    (B * LQ)          // 16384 = 128*128
#define MK    (B * LK)          // 20476
#define MKP   20480             // 160*128
#define NCH   160               // 32-row chunks per batch (160*32 = 5120)
#define TI    32                // query rows per window block

typedef float  f32x4  __attribute__((ext_vector_type(4)));
typedef __bf16 bf16x2 __attribute__((ext_vector_type(2)));
typedef __bf16 bf16x4 __attribute__((ext_vector_type(4)));
typedef __bf16 bf16x8 __attribute__((ext_vector_type(8)));

// async global->LDS, 16B per lane; lds must be wave-uniform (HW adds lane*16)
__device__ __forceinline__ void async16(void* lds, const void* g)
{
    __builtin_amdgcn_global_load_lds(
        (__attribute__((address_space(1))) void*)(g),
        (__attribute__((address_space(3))) void*)(lds),
        16, 0, 0);
}

// ---------------------------------------------------------------------------
// Kernel 1: LayerNorm -> bf16 for q/k/v in one dispatch (blockIdx.y selects).
// One wave per row; each lane owns cols [4t,4t+4) and [256+4t,256+4t+4).
// ---------------------------------------------------------------------------
__global__ __launch_bounds__(64) void ln_kernel(
    const float* __restrict__ q, const float* __restrict__ k,
    const float* __restrict__ v,
    const float* __restrict__ gq, const float* __restrict__ bq,
    const float* __restrict__ gk, const float* __restrict__ bk,
    const float* __restrict__ gv, const float* __restrict__ bv,
    __bf16* __restrict__ qn, __bf16* __restrict__ kn, __bf16* __restrict__ vn)
{
    const int z = blockIdx.y;
    const float *x, *g, *bb; __bf16* o; int M;
    if (z == 0)      { x = q; g = gq; bb = bq; o = qn; M = MQ; }
    else if (z == 1) { x = k; g = gk; bb = bk; o = kn; M = MK; }
    else             { x = v; g = gv; bb = bv; o = vn; M = MK; }
    const int r = blockIdx.x;
    if (r >= M) return;

    const int t = threadIdx.x;
    const float* xr = x + (long)r * D;
    const float4 a0 = *reinterpret_cast<const float4*>(xr + t * 4);
    const float4 a1 = *reinterpret_cast<const float4*>(xr + 256 + t * 4);

    float s  = a0.x + a0.y + a0.z + a0.w + a1.x + a1.y + a1.z + a1.w;
    float ss = a0.x*a0.x + a0.y*a0.y + a0.z*a0.z + a0.w*a0.w
             + a1.x*a1.x + a1.y*a1.y + a1.z*a1.z + a1.w*a1.w;
#pragma unroll
    for (int m = 1; m < 64; m <<= 1) {
        s  += __shfl_xor(s,  m, 64);
        ss += __shfl_xor(ss, m, 64);
    }
    const float mean = s * (1.f / (float)D);
    const float var  = ss * (1.f / (float)D) - mean * mean;
    const float rs   = rsqrtf(var + 1e-5f);

    const float4 g0 = *reinterpret_cast<const float4*>(g + t * 4);
    const float4 g1 = *reinterpret_cast<const float4*>(g + 256 + t * 4);
    const float4 b0 = *reinterpret_cast<const float4*>(bb + t * 4);
    const float4 b1 = *reinterpret_cast<const float4*>(bb + 256 + t * 4);

    bf16x4 o0, o1;
    o0[0] = (__bf16)((a0.x - mean) * rs * g0.x + b0.x);
    o0[1] = (__bf16)((a0.y - mean) * rs * g0.y + b0.y);
    o0[2] = (__bf16)((a0.z - mean) * rs * g0.z + b0.z);
    o0[3] = (__bf16)((a0.w - mean) * rs * g0.w + b0.w);
    o1[0] = (__bf16)((a1.x - mean) * rs * g1.x + b1.x);
    o1[1] = (__bf16)((a1.y - mean) * rs * g1.y + b1.y);
    o1[2] = (__bf16)((a1.z - mean) * rs * g1.z + b1.z);
    o1[3] = (__bf16)((a1.w - mean) * rs * g1.w + b1.w);

    __bf16* orow = o + (long)r * D;
    *reinterpret_cast<bf16x4*>(orow + t * 4)       = o0;
    *reinterpret_cast<bf16x4*>(orow + 256 + t * 4) = o1;
}

// ---------------------------------------------------------------------------
// Kernel 2: W[k][n] f32 -> Wt[n][k] bf16, 3 weights in one dispatch.
// Thread handles 8 consecutive k's for one n: coalesced reads, 16B writes.
// ---------------------------------------------------------------------------
__global__ __launch_bounds__(256) void wconv_kernel(
    const float* __restrict__ Wq, const float* __restrict__ Wk,
    const float* __restrict__ Wv,
    __bf16* __restrict__ wtq, __bf16* __restrict__ wtk, __bf16* __restrict__ wtv)
{
    const int z = blockIdx.z;
    const float* W = (z == 0) ? Wq : (z == 1) ? Wk : Wv;
    __bf16*     Wt = (z == 0) ? wtq : (z == 1) ? wtk : wtv;
    const int n  = blockIdx.x * 256 + threadIdx.x;
    const int k0 = blockIdx.y * 8;
    bf16x8 o;
#pragma unroll
    for (int j = 0; j < 8; ++j)
        o[j] = (__bf16)W[(long)(k0 + j) * D + n];
    *reinterpret_cast<bf16x8*>(Wt + (long)n * D + k0) = o;
}

// ---------------------------------------------------------------------------
// Kernel 3: qp = relu(qn @ Wq + bias) -> bf16.  m97-style: 128x128 tile,
// BK=32, global_load_lds dwordx4 staging, unpadded LDS (2-way alias is free).
// ---------------------------------------------------------------------------
__global__ __launch_bounds__(256) void gemm_q_kernel(
    const __bf16* __restrict__ A, const __bf16* __restrict__ Wt,
    const float* __restrict__ bias, __bf16* __restrict__ Cout)
{
    __shared__ __attribute__((aligned(16))) __bf16 As[128 * 32];
    __shared__ __attribute__((aligned(16))) __bf16 Bs[128 * 32];

    const int tid  = threadIdx.x;
    const int lane = tid & 63;
    const int wave = tid >> 6;
    const int quad = lane >> 4;
    const int l16  = lane & 15;
    const int wm   = wave >> 1;
    const int wn   = wave & 1;

    f32x4 acc[4][4];
#pragma unroll
    for (int i = 0; i < 4; ++i)
#pragma unroll
        for (int j = 0; j < 4; ++j)
            acc[i][j] = (f32x4){0.f, 0.f, 0.f, 0.f};

    const long arow0 = (long)blockIdx.x * 128;
    const long brow0 = (long)blockIdx.y * 128;
    const int  srow  = lane >> 2;      // 0..15 within a 16-row chunk
    const int  scol  = (lane & 3) * 8; // k-offset (8 bf16 = 16B)

    for (int k0 = 0; k0 < D; k0 += 32) {
#pragma unroll
        for (int h = 0; h < 2; ++h) {
            const int chunk = h * 4 + wave;          // 0..7
            const int row   = chunk * 16 + srow;
            async16(&As[chunk * 512], &A [(arow0 + row) * D + k0 + scol]);
            async16(&Bs[chunk * 512], &Wt[(brow0 + row) * D + k0 + scol]);
        }
        __syncthreads();

        bf16x8 af[4], bfr[4];
#pragma unroll
        for (int tm = 0; tm < 4; ++tm)
            af[tm] = *reinterpret_cast<const bf16x8*>(
                &As[(wm * 64 + tm * 16 + l16) * 32 + quad * 8]);
#pragma unroll
        for (int tn = 0; tn < 4; ++tn)
            bfr[tn] = *reinterpret_cast<const bf16x8*>(
                &Bs[(wn * 64 + tn * 16 + l16) * 32 + quad * 8]);

#pragma unroll
        for (int tm = 0; tm < 4; ++tm)
#pragma unroll
            for (int tn = 0; tn < 4; ++tn)
                acc[tm][tn] = __builtin_amdgcn_mfma_f32_16x16x32_bf16(
                    af[tm], bfr[tn], acc[tm][tn], 0, 0, 0);
        __syncthreads();
    }

    // C/D layout: col = lane&15, row = quad*4 + reg
#pragma unroll
    for (int tm = 0; tm < 4; ++tm) {
        const long row0 = arow0 + wm * 64 + tm * 16 + quad * 4;
#pragma unroll
        for (int tn = 0; tn < 4; ++tn) {
            const int col = (int)brow0 + wn * 64 + tn * 16 + l16;
            const float bv = bias[col];
#pragma unroll
            for (int r = 0; r < 4; ++r)
                Cout[(row0 + r) * D + col] =
                    (__bf16)fmaxf(acc[tm][tn][r] + bv, 0.f);
        }
    }
}

// ---------------------------------------------------------------------------
// Kernel 4: dual GEMM  kv = relu(kn@Wk + bwk) * (vn@Wv + bwv) -> bf16.
// Same structure, 4 LDS tiles (32 KB), 2 accumulator sets.
// ---------------------------------------------------------------------------
__global__ __launch_bounds__(256) void gemm_kv_kernel(
    const __bf16* __restrict__ Ak, const __bf16* __restrict__ Av,
    const __bf16* __restrict__ Wtk, const __bf16* __restrict__ Wtv,
    const float* __restrict__ bk, const float* __restrict__ bv,
    __bf16* __restrict__ kvout)
{
    __shared__ __attribute__((aligned(16))) __bf16 Ks [128 * 32];
    __shared__ __attribute__((aligned(16))) __bf16 Vs [128 * 32];
    __shared__ __attribute__((aligned(16))) __bf16 WKs[128 * 32];
    __shared__ __attribute__((aligned(16))) __bf16 WVs[128 * 32];

    const int tid  = threadIdx.x;
    const int lane = tid & 63;
    const int wave = tid >> 6;
    const int quad = lane >> 4;
    const int l16  = lane & 15;
    const int wm   = wave >> 1;
    const int wn   = wave & 1;

    f32x4 acck[4][4], accv[4][4];
#pragma unroll
    for (int i = 0; i < 4; ++i)
#pragma unroll
        for (int j = 0; j < 4; ++j) {
            acck[i][j] = (f32x4){0.f, 0.f, 0.f, 0.f};
            accv[i][j] = (f32x4){0.f, 0.f, 0.f, 0.f};
        }

    const long arow0 = (long)blockIdx.x * 128;
    const long brow0 = (long)blockIdx.y * 128;
    const int  srow  = lane >> 2;
    const int  scol  = (lane & 3) * 8;

    for (int k0 = 0; k0 < D; k0 += 32) {
#pragma unroll
        for (int h = 0; h < 2; ++h) {
            const int chunk = h * 4 + wave;
            const int row   = chunk * 16 + srow;
            async16(&Ks [chunk * 512], &Ak [(arow0 + row) * D + k0 + scol]);
            async16(&Vs [chunk * 512], &Av [(arow0 + row) * D + k0 + scol]);
            async16(&WKs[chunk * 512], &Wtk[(brow0 + row) * D + k0 + scol]);
            async16(&WVs[chunk * 512], &Wtv[(brow0 + row) * D + k0 + scol]);
        }
        __syncthreads();

        bf16x8 fa[4], fb[4];
#pragma unroll
        for (int tm = 0; tm < 4; ++tm)
            fa[tm] = *reinterpret_cast<const bf16x8*>(
                &Ks[(wm * 64 + tm * 16 + l16) * 32 + quad * 8]);
#pragma unroll
        for (int tn = 0; tn < 4; ++tn)
            fb[tn] = *reinterpret_cast<const bf16x8*>(
                &WKs[(wn * 64 + tn * 16 + l16) * 32 + quad * 8]);
#pragma unroll
        for (int tm = 0; tm < 4; ++tm)
#pragma unroll
            for (int tn = 0; tn < 4; ++tn)
                acck[tm][tn] = __builtin_amdgcn_mfma_f32_16x16x32_bf16(
                    fa[tm], fb[tn], acck[tm][tn], 0, 0, 0);

#pragma unroll
        for (int tm = 0; tm < 4; ++tm)
            fa[tm] = *reinterpret_cast<const bf16x8*>(
                &Vs[(wm * 64 + tm * 16 + l16) * 32 + quad * 8]);
#pragma unroll
        for (int tn = 0; tn < 4; ++tn)
            fb[tn] = *reinterpret_cast<const bf16x8*>(
                &WVs[(wn * 64 + tn * 16 + l16) * 32 + quad * 8]);
#pragma unroll
        for (int tm = 0; tm < 4; ++tm)
#pragma unroll
            for (int tn = 0; tn < 4; ++tn)
                accv[tm][tn] = __builtin_amdgcn_mfma_f32_16x16x32_bf16(
                    fa[tm], fb[tn], accv[tm][tn], 0, 0, 0);
        __syncthreads();
    }

#pragma unroll
    for (int tm = 0; tm < 4; ++tm) {
        const long row0 = arow0 + wm * 64 + tm * 16 + quad * 4;
#pragma unroll
        for (int tn = 0; tn < 4; ++tn) {
            const int col = (int)brow0 + wn * 64 + tn * 16 + l16;
            const float bkc = bk[col];
            const float bvc = bv[col];
#pragma unroll
            for (int r = 0; r < 4; ++r) {
                const float kp = fmaxf(acck[tm][tn][r] + bkc, 0.f);
                const float vp = accv[tm][tn][r] + bvc;
                kvout[(row0 + r) * D + col] = (__bf16)(kp * vp);
            }
        }
    }
}

// ---------------------------------------------------------------------------
// Kernel 5: 32-row chunk sums of kv (bf16 -> f32).  Csum[b][c][d].
// ---------------------------------------------------------------------------
__global__ __launch_bounds__(256) void chunk_kernel(
    const __bf16* __restrict__ kv, float* __restrict__ Csum)
{
    const int c    = blockIdx.x;
    const int b    = blockIdx.y;
    const int col2 = threadIdx.x * 2;
    const __bf16* base = kv + ((long)b * LK + (long)c * 32) * D + col2;
    float s0 = 0.f, s1 = 0.f;
#pragma unroll
    for (int j = 0; j < 32; ++j) {
        const bf16x2 vv = *reinterpret_cast<const bf16x2*>(base + (long)j * D);
        s0 += (float)vv[0];
        s1 += (float)vv[1];
    }
    float* o = Csum + ((long)b * NCH + c) * D + col2;
    o[0] = s0; o[1] = s1;
}

// ---------------------------------------------------------------------------
// Kernel 6: sliding window (1024) via chunk-sum init + rolling edges,
// times relu(qp).  TI=32 query rows/block, 2 cols/thread.
// ---------------------------------------------------------------------------
__global__ __launch_bounds__(256) void window_kernel(
    const __bf16* __restrict__ kv, const float* __restrict__ Csum,
    const __bf16* __restrict__ qpb, float* __restrict__ out)
{
    const int iq   = blockIdx.x;        // 0..127
    const int b    = blockIdx.y;
    const int i0   = iq * TI;
    const int col2 = threadIdx.x * 2;

    // init: sum of chunks iq .. iq+31  (rows [i0, i0+1024))
    const float* cs = Csum + (long)b * NCH * D + col2;
    float s0 = 0.f, s1 = 0.f;
#pragma unroll
    for (int c = 0; c < 32; ++c) {
        const float2 cv = *reinterpret_cast<const float2*>(cs + (long)(iq + c) * D);
        s0 += cv.x; s1 += cv.y;
    }

    const __bf16* kvb = kv  + (long)b * LK * D + col2;
    const __bf16* qb  = qpb + (long)b * LQ * D + col2;
    float*        ob  = out + (long)b * LQ * D + col2;

#pragma unroll 8
    for (int i = i0; i < i0 + TI; ++i) {
        const bf16x2 qv = *reinterpret_cast<const bf16x2*>(qb + (long)i * D);
        *reinterpret_cast<float2*>(ob + (long)i * D) =
            make_float2((float)qv[0] * s0, (float)qv[1] * s1);
        const bf16x2 lead  = *reinterpret_cast<const bf16x2*>(kvb + (long)(i + CACHE) * D);
        const bf16x2 trail = *reinterpret_cast<const bf16x2*>(kvb + (long)i * D);
        s0 += (float)lead[0] - (float)trail[0];
        s1 += (float)lead[1] - (float)trail[1];
    }
}

// ---------------------------------------------------------------------------
extern "C" void kernel_launch(void* const* d_in, const int* in_sizes, int n_in,
                              void* d_out, int out_size, void* d_ws, size_t ws_size,
                              hipStream_t stream)
{
    const float* q   = (const float*)d_in[0];
    const float* k   = (const float*)d_in[1];
    const float* v   = (const float*)d_in[2];
    const float* gq  = (const float*)d_in[3];
    const float* bq  = (const float*)d_in[4];
    const float* gk  = (const float*)d_in[5];
    const float* bk  = (const float*)d_in[6];
    const float* gv  = (const float*)d_in[7];
    const float* bv  = (const float*)d_in[8];
    const float* Wq  = (const float*)d_in[9];
    const float* bwq = (const float*)d_in[10];
    const float* Wk  = (const float*)d_in[11];
    const float* bwk = (const float*)d_in[12];
    const float* Wv  = (const float*)d_in[13];
    const float* bwv = (const float*)d_in[14];
    float* out = (float*)d_out;

    // Workspace layout (all segments multiple-of-4KB-ish, bf16 where possible)
    char* ws = (char*)d_ws;
    __bf16* qn   = (__bf16*)ws;                      // [MQ ][D] bf16
    __bf16* kn   = qn  + (long)MQ  * D;              // [MKP][D] bf16 (pads unused-garbage OK)
    __bf16* vn   = kn  + (long)MKP * D;              // [MKP][D] bf16
    __bf16* qpb  = vn  + (long)MKP * D;              // [MQ ][D] bf16  relu(qp)
    __bf16* kvb  = qpb + (long)MQ  * D;              // [MKP][D] bf16  relu(kp)*vp
    __bf16* wtq  = kvb + (long)MKP * D;              // [D][D] bf16 transposed
    __bf16* wtk  = wtq + (long)D * D;
    __bf16* wtv  = wtk + (long)D * D;
    float*  Csum = (float*)(wtv + (long)D * D);      // [B][NCH][D] f32

    // 1) LayerNorm -> bf16 (q,k,v in one dispatch)
    ln_kernel<<<dim3(MK, 3), 64, 0, stream>>>(q, k, v, gq, bq, gk, bk, gv, bv,
                                              qn, kn, vn);
    // 2) Weight transpose-convert (3 in one dispatch)
    wconv_kernel<<<dim3(2, 64, 3), 256, 0, stream>>>(Wq, Wk, Wv, wtq, wtk, wtv);

    // 3) qp = relu(qn@Wq + bwq)
    gemm_q_kernel<<<dim3(MQ / 128, D / 128), 256, 0, stream>>>(qn, wtq, bwq, qpb);

    // 4) kv = relu(kn@Wk + bwk) * (vn@Wv + bwv)
    gemm_kv_kernel<<<dim3(MKP / 128, D / 128), 256, 0, stream>>>(
        kn, vn, wtk, wtv, bwk, bwv, kvb);

    // 5) chunk sums (32 rows)
    chunk_kernel<<<dim3(NCH, B), 256, 0, stream>>>(kvb, Csum);

    // 6) window sum x relu(qp)
    window_kernel<<<dim3(LQ / TI, B), 256, 0, stream>>>(kvb, Csum, qpb, out);
}

// Round 3
// 252.031 us; speedup vs baseline: 1.3673x; 1.0833x over previous
//
#include <hip/hip_runtime.h>

// Problem constants
#define B     4
#define LQ    4096
#define LK    5119
#define D     512
#define CACHE 1024
#define MQ    (B * LQ)          // 16384 = 128*128
#define MK    (B * LK)          // 20476
#define MKP   20480             // 160*128
#define NCH   160               // 32-row chunks per batch (160*32 = 5120)
#define TI    32                // query rows per window block

typedef float  f32x4  __attribute__((ext_vector_type(4)));
typedef __bf16 bf16x2 __attribute__((ext_vector_type(2)));
typedef __bf16 bf16x4 __attribute__((ext_vector_type(4)));
typedef __bf16 bf16x8 __attribute__((ext_vector_type(8)));

// async global->LDS, 16B per lane; lds must be wave-uniform (HW adds lane*16)
__device__ __forceinline__ void async16(void* lds, const void* g)
{
    __builtin_amdgcn_global_load_lds(
        (__attribute__((address_space(1))) void*)(g),
        (__attribute__((address_space(3))) void*)(lds),
        16, 0, 0);
}

// ---------------------------------------------------------------------------
// Kernel 1: LayerNorm -> bf16 for q/k/v in one dispatch. 256 threads =
// 4 waves = 4 rows/block; each lane owns cols [4t,4t+4) and [256+4t,..).
// ---------------------------------------------------------------------------
__global__ __launch_bounds__(256) void ln_kernel(
    const float* __restrict__ q, const float* __restrict__ k,
    const float* __restrict__ v,
    const float* __restrict__ gq, const float* __restrict__ bq,
    const float* __restrict__ gk, const float* __restrict__ bk,
    const float* __restrict__ gv, const float* __restrict__ bv,
    __bf16* __restrict__ qn, __bf16* __restrict__ kn, __bf16* __restrict__ vn)
{
    const int z = blockIdx.y;
    const float *x, *g, *bb; __bf16* o; int M;
    if (z == 0)      { x = q; g = gq; bb = bq; o = qn; M = MQ; }
    else if (z == 1) { x = k; g = gk; bb = bk; o = kn; M = MK; }
    else             { x = v; g = gv; bb = bv; o = vn; M = MK; }
    const int r = blockIdx.x * 4 + (threadIdx.x >> 6);
    if (r >= M) return;

    const int t = threadIdx.x & 63;
    const float* xr = x + (long)r * D;
    const float4 a0 = *reinterpret_cast<const float4*>(xr + t * 4);
    const float4 a1 = *reinterpret_cast<const float4*>(xr + 256 + t * 4);

    float s  = a0.x + a0.y + a0.z + a0.w + a1.x + a1.y + a1.z + a1.w;
    float ss = a0.x*a0.x + a0.y*a0.y + a0.z*a0.z + a0.w*a0.w
             + a1.x*a1.x + a1.y*a1.y + a1.z*a1.z + a1.w*a1.w;
#pragma unroll
    for (int m = 1; m < 64; m <<= 1) {
        s  += __shfl_xor(s,  m, 64);
        ss += __shfl_xor(ss, m, 64);
    }
    const float mean = s * (1.f / (float)D);
    const float var  = ss * (1.f / (float)D) - mean * mean;
    const float rs   = rsqrtf(var + 1e-5f);

    const float4 g0 = *reinterpret_cast<const float4*>(g + t * 4);
    const float4 g1 = *reinterpret_cast<const float4*>(g + 256 + t * 4);
    const float4 b0 = *reinterpret_cast<const float4*>(bb + t * 4);
    const float4 b1 = *reinterpret_cast<const float4*>(bb + 256 + t * 4);

    bf16x4 o0, o1;
    o0[0] = (__bf16)((a0.x - mean) * rs * g0.x + b0.x);
    o0[1] = (__bf16)((a0.y - mean) * rs * g0.y + b0.y);
    o0[2] = (__bf16)((a0.z - mean) * rs * g0.z + b0.z);
    o0[3] = (__bf16)((a0.w - mean) * rs * g0.w + b0.w);
    o1[0] = (__bf16)((a1.x - mean) * rs * g1.x + b1.x);
    o1[1] = (__bf16)((a1.y - mean) * rs * g1.y + b1.y);
    o1[2] = (__bf16)((a1.z - mean) * rs * g1.z + b1.z);
    o1[3] = (__bf16)((a1.w - mean) * rs * g1.w + b1.w);

    __bf16* orow = o + (long)r * D;
    *reinterpret_cast<bf16x4*>(orow + t * 4)       = o0;
    *reinterpret_cast<bf16x4*>(orow + 256 + t * 4) = o1;
}

// ---------------------------------------------------------------------------
// Kernel 2: W[k][n] f32 -> Wt[n][k] bf16, 3 weights in one dispatch.
// ---------------------------------------------------------------------------
__global__ __launch_bounds__(256) void wconv_kernel(
    const float* __restrict__ Wq, const float* __restrict__ Wk,
    const float* __restrict__ Wv,
    __bf16* __restrict__ wtq, __bf16* __restrict__ wtk, __bf16* __restrict__ wtv)
{
    const int z = blockIdx.z;
    const float* W = (z == 0) ? Wq : (z == 1) ? Wk : Wv;
    __bf16*     Wt = (z == 0) ? wtq : (z == 1) ? wtk : wtv;
    const int n  = blockIdx.x * 256 + threadIdx.x;
    const int k0 = blockIdx.y * 8;
    bf16x8 o;
#pragma unroll
    for (int j = 0; j < 8; ++j)
        o[j] = (__bf16)W[(long)(k0 + j) * D + n];
    *reinterpret_cast<bf16x8*>(Wt + (long)n * D + k0) = o;
}

// ---------------------------------------------------------------------------
// Kernel 3: qp = relu(qn @ Wq + bias) -> bf16.  Tile 128x64, BK=32,
// 4 waves (2m x 2n), wave tile 64x32.  global_load_lds staging with
// XOR-swizzled k-chunks: physical slot s = q ^ ((row>>1)&3)  -> 2-way
// bank alias on ds_read_b128 (free) instead of 8-way.
// ---------------------------------------------------------------------------
__global__ __launch_bounds__(256, 2) void gemm_q_kernel(
    const __bf16* __restrict__ A, const __bf16* __restrict__ Wt,
    const float* __restrict__ bias, __bf16* __restrict__ Cout)
{
    __shared__ __attribute__((aligned(16))) __bf16 As[128 * 32];
    __shared__ __attribute__((aligned(16))) __bf16 Bs[64 * 32];

    const int tid  = threadIdx.x;
    const int lane = tid & 63;
    const int wave = tid >> 6;
    const int quad = lane >> 4;
    const int l16  = lane & 15;
    const int wm   = wave >> 1;      // 0..1
    const int wn   = wave & 1;       // 0..1

    f32x4 acc[4][2];
#pragma unroll
    for (int i = 0; i < 4; ++i)
#pragma unroll
        for (int j = 0; j < 2; ++j)
            acc[i][j] = (f32x4){0.f, 0.f, 0.f, 0.f};

    const long arow0 = (long)blockIdx.x * 128;
    const long brow0 = (long)blockIdx.y * 64;
    const int  srow  = lane >> 2;                       // 0..15
    const int  scol  = (((lane & 3) ^ ((srow >> 1) & 3)) * 8);  // swizzled src col
    const int  soff  = ((quad ^ ((l16 >> 1) & 3)) * 8);         // swizzled read col

    for (int k0 = 0; k0 < D; k0 += 32) {
        async16(&As[wave * 512],
                &A[(arow0 + wave * 16 + srow) * D + k0 + scol]);
        async16(&As[(wave + 4) * 512],
                &A[(arow0 + (wave + 4) * 16 + srow) * D + k0 + scol]);
        async16(&Bs[wave * 512],
                &Wt[(brow0 + wave * 16 + srow) * D + k0 + scol]);
        __syncthreads();

        bf16x8 af[4], bfr[2];
#pragma unroll
        for (int tm = 0; tm < 4; ++tm)
            af[tm] = *reinterpret_cast<const bf16x8*>(
                &As[(wm * 64 + tm * 16 + l16) * 32 + soff]);
#pragma unroll
        for (int tn = 0; tn < 2; ++tn)
            bfr[tn] = *reinterpret_cast<const bf16x8*>(
                &Bs[(wn * 32 + tn * 16 + l16) * 32 + soff]);

#pragma unroll
        for (int tm = 0; tm < 4; ++tm)
#pragma unroll
            for (int tn = 0; tn < 2; ++tn)
                acc[tm][tn] = __builtin_amdgcn_mfma_f32_16x16x32_bf16(
                    af[tm], bfr[tn], acc[tm][tn], 0, 0, 0);
        __syncthreads();
    }

    // C/D layout: col = lane&15, row = quad*4 + reg
#pragma unroll
    for (int tm = 0; tm < 4; ++tm) {
        const long row0 = arow0 + wm * 64 + tm * 16 + quad * 4;
#pragma unroll
        for (int tn = 0; tn < 2; ++tn) {
            const int col = (int)brow0 + wn * 32 + tn * 16 + l16;
            const float bv = bias[col];
#pragma unroll
            for (int r = 0; r < 4; ++r)
                Cout[(row0 + r) * D + col] =
                    (__bf16)fmaxf(acc[tm][tn][r] + bv, 0.f);
        }
    }
}

// ---------------------------------------------------------------------------
// Kernel 4: dual GEMM  kv = relu(kn@Wk + bwk) * (vn@Wv + bwv) -> bf16.
// Tile 128x64, wave tile 64x32 per GEMM -> 64 acc regs (vs 128 before).
// ---------------------------------------------------------------------------
__global__ __launch_bounds__(256, 2) void gemm_kv_kernel(
    const __bf16* __restrict__ Ak, const __bf16* __restrict__ Av,
    const __bf16* __restrict__ Wtk, const __bf16* __restrict__ Wtv,
    const float* __restrict__ bk, const float* __restrict__ bv,
    __bf16* __restrict__ kvout)
{
    __shared__ __attribute__((aligned(16))) __bf16 Ks [128 * 32];
    __shared__ __attribute__((aligned(16))) __bf16 Vs [128 * 32];
    __shared__ __attribute__((aligned(16))) __bf16 WKs[64 * 32];
    __shared__ __attribute__((aligned(16))) __bf16 WVs[64 * 32];

    const int tid  = threadIdx.x;
    const int lane = tid & 63;
    const int wave = tid >> 6;
    const int quad = lane >> 4;
    const int l16  = lane & 15;
    const int wm   = wave >> 1;
    const int wn   = wave & 1;

    f32x4 acck[4][2], accv[4][2];
#pragma unroll
    for (int i = 0; i < 4; ++i)
#pragma unroll
        for (int j = 0; j < 2; ++j) {
            acck[i][j] = (f32x4){0.f, 0.f, 0.f, 0.f};
            accv[i][j] = (f32x4){0.f, 0.f, 0.f, 0.f};
        }

    const long arow0 = (long)blockIdx.x * 128;
    const long brow0 = (long)blockIdx.y * 64;
    const int  srow  = lane >> 2;
    const int  scol  = (((lane & 3) ^ ((srow >> 1) & 3)) * 8);
    const int  soff  = ((quad ^ ((l16 >> 1) & 3)) * 8);

    for (int k0 = 0; k0 < D; k0 += 32) {
        async16(&Ks[wave * 512],
                &Ak[(arow0 + wave * 16 + srow) * D + k0 + scol]);
        async16(&Ks[(wave + 4) * 512],
                &Ak[(arow0 + (wave + 4) * 16 + srow) * D + k0 + scol]);
        async16(&Vs[wave * 512],
                &Av[(arow0 + wave * 16 + srow) * D + k0 + scol]);
        async16(&Vs[(wave + 4) * 512],
                &Av[(arow0 + (wave + 4) * 16 + srow) * D + k0 + scol]);
        async16(&WKs[wave * 512],
                &Wtk[(brow0 + wave * 16 + srow) * D + k0 + scol]);
        async16(&WVs[wave * 512],
                &Wtv[(brow0 + wave * 16 + srow) * D + k0 + scol]);
        __syncthreads();

        bf16x8 fa[4], fb[2];
#pragma unroll
        for (int tm = 0; tm < 4; ++tm)
            fa[tm] = *reinterpret_cast<const bf16x8*>(
                &Ks[(wm * 64 + tm * 16 + l16) * 32 + soff]);
#pragma unroll
        for (int tn = 0; tn < 2; ++tn)
            fb[tn] = *reinterpret_cast<const bf16x8*>(
                &WKs[(wn * 32 + tn * 16 + l16) * 32 + soff]);
#pragma unroll
        for (int tm = 0; tm < 4; ++tm)
#pragma unroll
            for (int tn = 0; tn < 2; ++tn)
                acck[tm][tn] = __builtin_amdgcn_mfma_f32_16x16x32_bf16(
                    fa[tm], fb[tn], acck[tm][tn], 0, 0, 0);

#pragma unroll
        for (int tm = 0; tm < 4; ++tm)
            fa[tm] = *reinterpret_cast<const bf16x8*>(
                &Vs[(wm * 64 + tm * 16 + l16) * 32 + soff]);
#pragma unroll
        for (int tn = 0; tn < 2; ++tn)
            fb[tn] = *reinterpret_cast<const bf16x8*>(
                &WVs[(wn * 32 + tn * 16 + l16) * 32 + soff]);
#pragma unroll
        for (int tm = 0; tm < 4; ++tm)
#pragma unroll
            for (int tn = 0; tn < 2; ++tn)
                accv[tm][tn] = __builtin_amdgcn_mfma_f32_16x16x32_bf16(
                    fa[tm], fb[tn], accv[tm][tn], 0, 0, 0);
        __syncthreads();
    }

#pragma unroll
    for (int tm = 0; tm < 4; ++tm) {
        const long row0 = arow0 + wm * 64 + tm * 16 + quad * 4;
#pragma unroll
        for (int tn = 0; tn < 2; ++tn) {
            const int col = (int)brow0 + wn * 32 + tn * 16 + l16;
            const float bkc = bk[col];
            const float bvc = bv[col];
#pragma unroll
            for (int r = 0; r < 4; ++r) {
                const float kp = fmaxf(acck[tm][tn][r] + bkc, 0.f);
                const float vp = accv[tm][tn][r] + bvc;
                kvout[(row0 + r) * D + col] = (__bf16)(kp * vp);
            }
        }
    }
}

// ---------------------------------------------------------------------------
// Kernel 5: 32-row chunk sums of kv (bf16 -> f32).  Csum[b][c][d].
// ---------------------------------------------------------------------------
__global__ __launch_bounds__(256) void chunk_kernel(
    const __bf16* __restrict__ kv, float* __restrict__ Csum)
{
    const int c    = blockIdx.x;
    const int b    = blockIdx.y;
    const int col2 = threadIdx.x * 2;
    const __bf16* base = kv + ((long)b * LK + (long)c * 32) * D + col2;
    float s0 = 0.f, s1 = 0.f;
#pragma unroll
    for (int j = 0; j < 32; ++j) {
        const bf16x2 vv = *reinterpret_cast<const bf16x2*>(base + (long)j * D);
        s0 += (float)vv[0];
        s1 += (float)vv[1];
    }
    float* o = Csum + ((long)b * NCH + c) * D + col2;
    o[0] = s0; o[1] = s1;
}

// ---------------------------------------------------------------------------
// Kernel 6: sliding window (1024) via chunk-sum init + rolling edges,
// times relu(qp).  TI=32 query rows/block, 2 cols/thread.
// ---------------------------------------------------------------------------
__global__ __launch_bounds__(256) void window_kernel(
    const __bf16* __restrict__ kv, const float* __restrict__ Csum,
    const __bf16* __restrict__ qpb, float* __restrict__ out)
{
    const int iq   = blockIdx.x;        // 0..127
    const int b    = blockIdx.y;
    const int i0   = iq * TI;
    const int col2 = threadIdx.x * 2;

    const float* cs = Csum + (long)b * NCH * D + col2;
    float s0 = 0.f, s1 = 0.f;
#pragma unroll
    for (int c = 0; c < 32; ++c) {
        const float2 cv = *reinterpret_cast<const float2*>(cs + (long)(iq + c) * D);
        s0 += cv.x; s1 += cv.y;
    }

    const __bf16* kvb = kv  + (long)b * LK * D + col2;
    const __bf16* qb  = qpb + (long)b * LQ * D + col2;
    float*        ob  = out + (long)b * LQ * D + col2;

#pragma unroll 8
    for (int i = i0; i < i0 + TI; ++i) {
        const bf16x2 qv = *reinterpret_cast<const bf16x2*>(qb + (long)i * D);
        *reinterpret_cast<float2*>(ob + (long)i * D) =
            make_float2((float)qv[0] * s0, (float)qv[1] * s1);
        const bf16x2 lead  = *reinterpret_cast<const bf16x2*>(kvb + (long)(i + CACHE) * D);
        const bf16x2 trail = *reinterpret_cast<const bf16x2*>(kvb + (long)i * D);
        s0 += (float)lead[0] - (float)trail[0];
        s1 += (float)lead[1] - (float)trail[1];
    }
}

// ---------------------------------------------------------------------------
extern "C" void kernel_launch(void* const* d_in, const int* in_sizes, int n_in,
                              void* d_out, int out_size, void* d_ws, size_t ws_size,
                              hipStream_t stream)
{
    const float* q   = (const float*)d_in[0];
    const float* k   = (const float*)d_in[1];
    const float* v   = (const float*)d_in[2];
    const float* gq  = (const float*)d_in[3];
    const float* bq  = (const float*)d_in[4];
    const float* gk  = (const float*)d_in[5];
    const float* bk  = (const float*)d_in[6];
    const float* gv  = (const float*)d_in[7];
    const float* bv  = (const float*)d_in[8];
    const float* Wq  = (const float*)d_in[9];
    const float* bwq = (const float*)d_in[10];
    const float* Wk  = (const float*)d_in[11];
    const float* bwk = (const float*)d_in[12];
    const float* Wv  = (const float*)d_in[13];
    const float* bwv = (const float*)d_in[14];
    float* out = (float*)d_out;

    // Workspace layout
    char* ws = (char*)d_ws;
    __bf16* qn   = (__bf16*)ws;                      // [MQ ][D] bf16
    __bf16* kn   = qn  + (long)MQ  * D;              // [MKP][D] bf16
    __bf16* vn   = kn  + (long)MKP * D;              // [MKP][D] bf16
    __bf16* qpb  = vn  + (long)MKP * D;              // [MQ ][D] bf16  relu(qp)
    __bf16* kvb  = qpb + (long)MQ  * D;              // [MKP][D] bf16  relu(kp)*vp
    __bf16* wtq  = kvb + (long)MKP * D;              // [D][D] bf16 transposed
    __bf16* wtk  = wtq + (long)D * D;
    __bf16* wtv  = wtk + (long)D * D;
    float*  Csum = (float*)(wtv + (long)D * D);      // [B][NCH][D] f32

    // 1) LayerNorm -> bf16 (q,k,v in one dispatch; 4 rows/block)
    ln_kernel<<<dim3(5120, 3), 256, 0, stream>>>(q, k, v, gq, bq, gk, bk, gv, bv,
                                                 qn, kn, vn);
    // 2) Weight transpose-convert (3 in one dispatch)
    wconv_kernel<<<dim3(2, 64, 3), 256, 0, stream>>>(Wq, Wk, Wv, wtq, wtk, wtv);

    // 3) qp = relu(qn@Wq + bwq)
    gemm_q_kernel<<<dim3(MQ / 128, D / 64), 256, 0, stream>>>(qn, wtq, bwq, qpb);

    // 4) kv = relu(kn@Wk + bwk) * (vn@Wv + bwv)
    gemm_kv_kernel<<<dim3(MKP / 128, D / 64), 256, 0, stream>>>(
        kn, vn, wtk, wtv, bwk, bwv, kvb);

    // 5) chunk sums (32 rows)
    chunk_kernel<<<dim3(NCH, B), 256, 0, stream>>>(kvb, Csum);

    // 6) window sum x relu(qp)
    window_kernel<<<dim3(LQ / TI, B), 256, 0, stream>>>(kvb, Csum, qpb, out);
}

// Round 4
// 237.896 us; speedup vs baseline: 1.4485x; 1.0594x over previous
//
#include <hip/hip_runtime.h>

// Problem constants
#define B     4
#define LQ    4096
#define LK    5119
#define D     512
#define CACHE 1024
#define MQ    (B * LQ)          // 16384 = 128*128
#define MK    (B * LK)          // 20476
#define MKP   20480             // 160*128
#define NCH   160               // 32-row chunks per batch (160*32 = 5120)
#define TI    32                // query rows per window block

typedef float  f32x4  __attribute__((ext_vector_type(4)));
typedef __bf16 bf16x2 __attribute__((ext_vector_type(2)));
typedef __bf16 bf16x4 __attribute__((ext_vector_type(4)));
typedef __bf16 bf16x8 __attribute__((ext_vector_type(8)));

// async global->LDS, 16B per lane; lds base wave-uniform (HW adds lane*16)
__device__ __forceinline__ void async16(void* lds, const void* g)
{
    __builtin_amdgcn_global_load_lds(
        (__attribute__((address_space(1))) void*)(g),
        (__attribute__((address_space(3))) void*)(lds),
        16, 0, 0);
}

// ---------------------------------------------------------------------------
// Kernel 1: LayerNorm -> bf16, q/k/v in one dispatch.  Half-wave (32 lanes)
// per row, 8 rows per 256-thread block; each lane owns 16 consecutive cols.
// ---------------------------------------------------------------------------
__global__ __launch_bounds__(256) void ln_kernel(
    const float* __restrict__ q, const float* __restrict__ k,
    const float* __restrict__ v,
    const float* __restrict__ gq, const float* __restrict__ bq,
    const float* __restrict__ gk, const float* __restrict__ bk,
    const float* __restrict__ gv, const float* __restrict__ bv,
    __bf16* __restrict__ qn, __bf16* __restrict__ kn, __bf16* __restrict__ vn)
{
    const int z = blockIdx.y;
    const float *x, *g, *bb; __bf16* o; int M;
    if (z == 0)      { x = q; g = gq; bb = bq; o = qn; M = MQ; }
    else if (z == 1) { x = k; g = gk; bb = bk; o = kn; M = MK; }
    else             { x = v; g = gv; bb = bv; o = vn; M = MK; }
    const int r = blockIdx.x * 8 + (threadIdx.x >> 5);
    if (r >= M) return;

    const int c0 = (threadIdx.x & 31) * 16;
    const float* xr = x + (long)r * D + c0;

    float4 a[4];
#pragma unroll
    for (int j = 0; j < 4; ++j)
        a[j] = *reinterpret_cast<const float4*>(xr + j * 4);

    float s = 0.f, ss = 0.f;
#pragma unroll
    for (int j = 0; j < 4; ++j) {
        s  += a[j].x + a[j].y + a[j].z + a[j].w;
        ss += a[j].x*a[j].x + a[j].y*a[j].y + a[j].z*a[j].z + a[j].w*a[j].w;
    }
#pragma unroll
    for (int m = 1; m <= 16; m <<= 1) {     // reduce within 32-lane half
        s  += __shfl_xor(s,  m, 64);
        ss += __shfl_xor(ss, m, 64);
    }
    const float mean = s * (1.f / (float)D);
    const float var  = ss * (1.f / (float)D) - mean * mean;
    const float rs   = rsqrtf(var + 1e-5f);

    bf16x8 o0, o1;
#pragma unroll
    for (int j = 0; j < 4; ++j) {
        const float4 gv4 = *reinterpret_cast<const float4*>(g  + c0 + j * 4);
        const float4 bv4 = *reinterpret_cast<const float4*>(bb + c0 + j * 4);
        const float y0 = (a[j].x - mean) * rs * gv4.x + bv4.x;
        const float y1 = (a[j].y - mean) * rs * gv4.y + bv4.y;
        const float y2 = (a[j].z - mean) * rs * gv4.z + bv4.z;
        const float y3 = (a[j].w - mean) * rs * gv4.w + bv4.w;
        if (j < 2) {
            o0[j*4+0] = (__bf16)y0; o0[j*4+1] = (__bf16)y1;
            o0[j*4+2] = (__bf16)y2; o0[j*4+3] = (__bf16)y3;
        } else {
            o1[(j-2)*4+0] = (__bf16)y0; o1[(j-2)*4+1] = (__bf16)y1;
            o1[(j-2)*4+2] = (__bf16)y2; o1[(j-2)*4+3] = (__bf16)y3;
        }
    }
    __bf16* orow = o + (long)r * D + c0;
    *reinterpret_cast<bf16x8*>(orow)     = o0;
    *reinterpret_cast<bf16x8*>(orow + 8) = o1;
}

// ---------------------------------------------------------------------------
// Kernel 2: W[k][n] f32 -> Wt[n][k] bf16, 3 weights in one dispatch.
// ---------------------------------------------------------------------------
__global__ __launch_bounds__(256) void wconv_kernel(
    const float* __restrict__ Wq, const float* __restrict__ Wk,
    const float* __restrict__ Wv,
    __bf16* __restrict__ wtq, __bf16* __restrict__ wtk, __bf16* __restrict__ wtv)
{
    const int z = blockIdx.z;
    const float* W = (z == 0) ? Wq : (z == 1) ? Wk : Wv;
    __bf16*     Wt = (z == 0) ? wtq : (z == 1) ? wtk : wtv;
    const int n  = blockIdx.x * 256 + threadIdx.x;
    const int k0 = blockIdx.y * 8;
    bf16x8 o;
#pragma unroll
    for (int j = 0; j < 8; ++j)
        o[j] = (__bf16)W[(long)(k0 + j) * D + n];
    *reinterpret_cast<bf16x8*>(Wt + (long)n * D + k0) = o;
}

// ---------------------------------------------------------------------------
// Kernel 3: qp = relu(qn @ Wq + bias) -> bf16.  Tile 128x128, BK=64,
// 4 waves (2x2), wave tile 64x64 (acc 4x4).  XOR-swizzled 16B chunks:
// phys_chunk = k_chunk ^ (row & 7)  -> per-b128 bank load = 8-word floor.
// ---------------------------------------------------------------------------
__global__ __launch_bounds__(256, 2) void gemm_q_kernel(
    const __bf16* __restrict__ A, const __bf16* __restrict__ Wt,
    const float* __restrict__ bias, __bf16* __restrict__ Cout)
{
    __shared__ __attribute__((aligned(16))) __bf16 As[128 * 64];
    __shared__ __attribute__((aligned(16))) __bf16 Bs[128 * 64];

    const int tid  = threadIdx.x;
    const int lane = tid & 63;
    const int wave = tid >> 6;
    const int quad = lane >> 4;
    const int l16  = lane & 15;
    const int wm   = wave >> 1;      // 0..1
    const int wn   = wave & 1;       // 0..1

    f32x4 acc[4][4];
#pragma unroll
    for (int i = 0; i < 4; ++i)
#pragma unroll
        for (int j = 0; j < 4; ++j)
            acc[i][j] = (f32x4){0.f, 0.f, 0.f, 0.f};

    const long arow0 = (long)blockIdx.x * 128;
    const long brow0 = (long)blockIdx.y * 128;
    const int  lrow  = lane >> 3;                    // 0..7 within row-group
    const int  lcs   = ((lane & 7) ^ lrow) * 8;      // swizzled k-col (bf16)

    for (int k0 = 0; k0 < D; k0 += 64) {
#pragma unroll
        for (int j = 0; j < 4; ++j) {
            const int r0  = (j * 4 + wave) * 8;      // 0,8,...,120
            const int row = r0 + lrow;
            async16(&As[r0 * 64], &A [(arow0 + row) * D + k0 + lcs]);
            async16(&Bs[r0 * 64], &Wt[(brow0 + row) * D + k0 + lcs]);
        }
        __syncthreads();

        bf16x8 af[4][2], bf[4][2];
#pragma unroll
        for (int tm = 0; tm < 4; ++tm) {
            const int m = wm * 64 + tm * 16 + l16;
#pragma unroll
            for (int kh = 0; kh < 2; ++kh)
                af[tm][kh] = *reinterpret_cast<const bf16x8*>(
                    &As[m * 64 + (((kh * 4 + quad) ^ (m & 7)) * 8)]);
        }
#pragma unroll
        for (int tn = 0; tn < 4; ++tn) {
            const int n = wn * 64 + tn * 16 + l16;
#pragma unroll
            for (int kh = 0; kh < 2; ++kh)
                bf[tn][kh] = *reinterpret_cast<const bf16x8*>(
                    &Bs[n * 64 + (((kh * 4 + quad) ^ (n & 7)) * 8)]);
        }

#pragma unroll
        for (int kh = 0; kh < 2; ++kh)
#pragma unroll
            for (int tm = 0; tm < 4; ++tm)
#pragma unroll
                for (int tn = 0; tn < 4; ++tn)
                    acc[tm][tn] = __builtin_amdgcn_mfma_f32_16x16x32_bf16(
                        af[tm][kh], bf[tn][kh], acc[tm][tn], 0, 0, 0);
        __syncthreads();
    }

    // C/D layout: col = lane&15, row = quad*4 + reg
#pragma unroll
    for (int tm = 0; tm < 4; ++tm) {
        const long row0 = arow0 + wm * 64 + tm * 16 + quad * 4;
#pragma unroll
        for (int tn = 0; tn < 4; ++tn) {
            const int col = (int)brow0 + wn * 64 + tn * 16 + l16;
            const float bv = bias[col];
#pragma unroll
            for (int r = 0; r < 4; ++r)
                Cout[(row0 + r) * D + col] =
                    (__bf16)fmaxf(acc[tm][tn][r] + bv, 0.f);
        }
    }
}

// ---------------------------------------------------------------------------
// Kernel 4: dual GEMM  kv = relu(kn@Wk + bwk) * (vn@Wv + bwv) -> bf16.
// Tile 128x64, BK=64, wave tile 64x32 per GEMM (acc 2x(4x2)).  48 KB LDS.
// ---------------------------------------------------------------------------
__global__ __launch_bounds__(256, 2) void gemm_kv_kernel(
    const __bf16* __restrict__ Ak, const __bf16* __restrict__ Av,
    const __bf16* __restrict__ Wtk, const __bf16* __restrict__ Wtv,
    const float* __restrict__ bk, const float* __restrict__ bv,
    __bf16* __restrict__ kvout)
{
    __shared__ __attribute__((aligned(16))) __bf16 Ks [128 * 64];
    __shared__ __attribute__((aligned(16))) __bf16 Vs [128 * 64];
    __shared__ __attribute__((aligned(16))) __bf16 WKs[64 * 64];
    __shared__ __attribute__((aligned(16))) __bf16 WVs[64 * 64];

    const int tid  = threadIdx.x;
    const int lane = tid & 63;
    const int wave = tid >> 6;
    const int quad = lane >> 4;
    const int l16  = lane & 15;
    const int wm   = wave >> 1;
    const int wn   = wave & 1;

    f32x4 acck[4][2], accv[4][2];
#pragma unroll
    for (int i = 0; i < 4; ++i)
#pragma unroll
        for (int j = 0; j < 2; ++j) {
            acck[i][j] = (f32x4){0.f, 0.f, 0.f, 0.f};
            accv[i][j] = (f32x4){0.f, 0.f, 0.f, 0.f};
        }

    const long arow0 = (long)blockIdx.x * 128;
    const long brow0 = (long)blockIdx.y * 64;
    const int  lrow  = lane >> 3;
    const int  lcs   = ((lane & 7) ^ lrow) * 8;

    for (int k0 = 0; k0 < D; k0 += 64) {
#pragma unroll
        for (int j = 0; j < 4; ++j) {
            const int r0  = (j * 4 + wave) * 8;
            const int row = r0 + lrow;
            async16(&Ks[r0 * 64], &Ak[(arow0 + row) * D + k0 + lcs]);
            async16(&Vs[r0 * 64], &Av[(arow0 + row) * D + k0 + lcs]);
        }
#pragma unroll
        for (int j = 0; j < 2; ++j) {
            const int r0  = (j * 4 + wave) * 8;      // 0..56
            const int row = r0 + lrow;
            async16(&WKs[r0 * 64], &Wtk[(brow0 + row) * D + k0 + lcs]);
            async16(&WVs[r0 * 64], &Wtv[(brow0 + row) * D + k0 + lcs]);
        }
        __syncthreads();

        bf16x8 fa[4][2], fb[2][2];
        // --- K gemm ---
#pragma unroll
        for (int tm = 0; tm < 4; ++tm) {
            const int m = wm * 64 + tm * 16 + l16;
#pragma unroll
            for (int kh = 0; kh < 2; ++kh)
                fa[tm][kh] = *reinterpret_cast<const bf16x8*>(
                    &Ks[m * 64 + (((kh * 4 + quad) ^ (m & 7)) * 8)]);
        }
#pragma unroll
        for (int tn = 0; tn < 2; ++tn) {
            const int n = wn * 32 + tn * 16 + l16;
#pragma unroll
            for (int kh = 0; kh < 2; ++kh)
                fb[tn][kh] = *reinterpret_cast<const bf16x8*>(
                    &WKs[n * 64 + (((kh * 4 + quad) ^ (n & 7)) * 8)]);
        }
#pragma unroll
        for (int kh = 0; kh < 2; ++kh)
#pragma unroll
            for (int tm = 0; tm < 4; ++tm)
#pragma unroll
                for (int tn = 0; tn < 2; ++tn)
                    acck[tm][tn] = __builtin_amdgcn_mfma_f32_16x16x32_bf16(
                        fa[tm][kh], fb[tn][kh], acck[tm][tn], 0, 0, 0);
        // --- V gemm ---
#pragma unroll
        for (int tm = 0; tm < 4; ++tm) {
            const int m = wm * 64 + tm * 16 + l16;
#pragma unroll
            for (int kh = 0; kh < 2; ++kh)
                fa[tm][kh] = *reinterpret_cast<const bf16x8*>(
                    &Vs[m * 64 + (((kh * 4 + quad) ^ (m & 7)) * 8)]);
        }
#pragma unroll
        for (int tn = 0; tn < 2; ++tn) {
            const int n = wn * 32 + tn * 16 + l16;
#pragma unroll
            for (int kh = 0; kh < 2; ++kh)
                fb[tn][kh] = *reinterpret_cast<const bf16x8*>(
                    &WVs[n * 64 + (((kh * 4 + quad) ^ (n & 7)) * 8)]);
        }
#pragma unroll
        for (int kh = 0; kh < 2; ++kh)
#pragma unroll
            for (int tm = 0; tm < 4; ++tm)
#pragma unroll
                for (int tn = 0; tn < 2; ++tn)
                    accv[tm][tn] = __builtin_amdgcn_mfma_f32_16x16x32_bf16(
                        fa[tm][kh], fb[tn][kh], accv[tm][tn], 0, 0, 0);
        __syncthreads();
    }

#pragma unroll
    for (int tm = 0; tm < 4; ++tm) {
        const long row0 = arow0 + wm * 64 + tm * 16 + quad * 4;
#pragma unroll
        for (int tn = 0; tn < 2; ++tn) {
            const int col = (int)brow0 + wn * 32 + tn * 16 + l16;
            const float bkc = bk[col];
            const float bvc = bv[col];
#pragma unroll
            for (int r = 0; r < 4; ++r) {
                const float kp = fmaxf(acck[tm][tn][r] + bkc, 0.f);
                const float vp = accv[tm][tn][r] + bvc;
                kvout[(row0 + r) * D + col] = (__bf16)(kp * vp);
            }
        }
    }
}

// ---------------------------------------------------------------------------
// Kernel 5: 32-row chunk sums of kv (bf16 -> f32).  Csum[b][c][d].
// ---------------------------------------------------------------------------
__global__ __launch_bounds__(256) void chunk_kernel(
    const __bf16* __restrict__ kv, float* __restrict__ Csum)
{
    const int c    = blockIdx.x;
    const int b    = blockIdx.y;
    const int col2 = threadIdx.x * 2;
    const __bf16* base = kv + ((long)b * LK + (long)c * 32) * D + col2;
    float s0 = 0.f, s1 = 0.f;
#pragma unroll
    for (int j = 0; j < 32; ++j) {
        const bf16x2 vv = *reinterpret_cast<const bf16x2*>(base + (long)j * D);
        s0 += (float)vv[0];
        s1 += (float)vv[1];
    }
    float* o = Csum + ((long)b * NCH + c) * D + col2;
    o[0] = s0; o[1] = s1;
}

// ---------------------------------------------------------------------------
// Kernel 6: sliding window (1024) via chunk-sum init + rolling edges,
// times relu(qp).  TI=32 query rows/block, 2 cols/thread.
// ---------------------------------------------------------------------------
__global__ __launch_bounds__(256) void window_kernel(
    const __bf16* __restrict__ kv, const float* __restrict__ Csum,
    const __bf16* __restrict__ qpb, float* __restrict__ out)
{
    const int iq   = blockIdx.x;        // 0..127
    const int b    = blockIdx.y;
    const int i0   = iq * TI;
    const int col2 = threadIdx.x * 2;

    const float* cs = Csum + (long)b * NCH * D + col2;
    float s0 = 0.f, s1 = 0.f;
#pragma unroll
    for (int c = 0; c < 32; ++c) {
        const float2 cv = *reinterpret_cast<const float2*>(cs + (long)(iq + c) * D);
        s0 += cv.x; s1 += cv.y;
    }

    const __bf16* kvb = kv  + (long)b * LK * D + col2;
    const __bf16* qb  = qpb + (long)b * LQ * D + col2;
    float*        ob  = out + (long)b * LQ * D + col2;

#pragma unroll 8
    for (int i = i0; i < i0 + TI; ++i) {
        const bf16x2 qv = *reinterpret_cast<const bf16x2*>(qb + (long)i * D);
        *reinterpret_cast<float2*>(ob + (long)i * D) =
            make_float2((float)qv[0] * s0, (float)qv[1] * s1);
        const bf16x2 lead  = *reinterpret_cast<const bf16x2*>(kvb + (long)(i + CACHE) * D);
        const bf16x2 trail = *reinterpret_cast<const bf16x2*>(kvb + (long)i * D);
        s0 += (float)lead[0] - (float)trail[0];
        s1 += (float)lead[1] - (float)trail[1];
    }
}

// ---------------------------------------------------------------------------
extern "C" void kernel_launch(void* const* d_in, const int* in_sizes, int n_in,
                              void* d_out, int out_size, void* d_ws, size_t ws_size,
                              hipStream_t stream)
{
    const float* q   = (const float*)d_in[0];
    const float* k   = (const float*)d_in[1];
    const float* v   = (const float*)d_in[2];
    const float* gq  = (const float*)d_in[3];
    const float* bq  = (const float*)d_in[4];
    const float* gk  = (const float*)d_in[5];
    const float* bk  = (const float*)d_in[6];
    const float* gv  = (const float*)d_in[7];
    const float* bv  = (const float*)d_in[8];
    const float* Wq  = (const float*)d_in[9];
    const float* bwq = (const float*)d_in[10];
    const float* Wk  = (const float*)d_in[11];
    const float* bwk = (const float*)d_in[12];
    const float* Wv  = (const float*)d_in[13];
    const float* bwv = (const float*)d_in[14];
    float* out = (float*)d_out;

    // Workspace layout
    char* ws = (char*)d_ws;
    __bf16* qn   = (__bf16*)ws;                      // [MQ ][D] bf16
    __bf16* kn   = qn  + (long)MQ  * D;              // [MKP][D] bf16
    __bf16* vn   = kn  + (long)MKP * D;              // [MKP][D] bf16
    __bf16* qpb  = vn  + (long)MKP * D;              // [MQ ][D] bf16  relu(qp)
    __bf16* kvb  = qpb + (long)MQ  * D;              // [MKP][D] bf16  relu(kp)*vp
    __bf16* wtq  = kvb + (long)MKP * D;              // [D][D] bf16 transposed
    __bf16* wtk  = wtq + (long)D * D;
    __bf16* wtv  = wtk + (long)D * D;
    float*  Csum = (float*)(wtv + (long)D * D);      // [B][NCH][D] f32

    // 1) LayerNorm -> bf16 (q,k,v; half-wave per row, 8 rows/block)
    ln_kernel<<<dim3(2560, 3), 256, 0, stream>>>(q, k, v, gq, bq, gk, bk, gv, bv,
                                                 qn, kn, vn);
    // 2) Weight transpose-convert (3 in one dispatch)
    wconv_kernel<<<dim3(2, 64, 3), 256, 0, stream>>>(Wq, Wk, Wv, wtq, wtk, wtv);

    // 3) qp = relu(qn@Wq + bwq)
    gemm_q_kernel<<<dim3(MQ / 128, D / 128), 256, 0, stream>>>(qn, wtq, bwq, qpb);

    // 4) kv = relu(kn@Wk + bwk) * (vn@Wv + bwv)
    gemm_kv_kernel<<<dim3(MKP / 128, D / 64), 256, 0, stream>>>(
        kn, vn, wtk, wtv, bwk, bwv, kvb);

    // 5) chunk sums (32 rows)
    chunk_kernel<<<dim3(NCH, B), 256, 0, stream>>>(kvb, Csum);

    // 6) window sum x relu(qp)
    window_kernel<<<dim3(LQ / TI, B), 256, 0, stream>>>(kvb, Csum, qpb, out);
}